// Round 1
// baseline (44.418 us; speedup 1.0000x reference)
//
#include <hip/hip_runtime.h>

// LIF recurrence: x [T=256, B=32, H=64, W=64] f32 -> spikes same shape.
// Independent across the 131072 spatial elements; sequential over T.
// Memory-bound: 128 MiB in + 128 MiB out => floor ~42us at 6.3 TB/s.
//
// Numerics: reference (numpy/XLA f32) does NOT contract mul+add into FMA.
// Spikes are a hard threshold (v_dec > 1.0), so a single differently-rounded
// FMA can flip a spike (absmax jumps to 1.0). All recurrence arithmetic uses
// __fmul_rn/__fadd_rn/__fsub_rn to pin the exact f32 op sequence.

#define T_STEPS 256
#define UNROLL 8

__global__ __launch_bounds__(128) void lif_kernel(
    const float2* __restrict__ x, float2* __restrict__ out,
    const float* __restrict__ tsi_p, const float* __restrict__ tmi_p,
    int n2)
{
    int idx = blockIdx.x * blockDim.x + threadIdx.x;
    if (idx >= n2) return;

    const float tmi = *tmi_p;
    const float tsi = *tsi_p;
    // a = DT * tau_mem_inv ; b = 1 - DT * tau_syn_inv  (exact ref op order)
    const float a = __fmul_rn(0.001f, tmi);
    const float b = __fsub_rn(1.0f, __fmul_rn(0.001f, tsi));

    const float2* xp = x + idx;
    float2*       op = out + idx;

    float v0 = 0.f, i0 = 0.f, v1 = 0.f, i1 = 0.f;
    float2 cur[UNROLL], nxt[UNROLL];

#pragma unroll
    for (int j = 0; j < UNROLL; ++j) cur[j] = xp[(size_t)j * n2];
    xp += (size_t)UNROLL * n2;

    for (int t = 0; t < T_STEPS; t += UNROLL) {
        // prefetch next chunk while computing current (double buffer)
        if (t + UNROLL < T_STEPS) {
#pragma unroll
            for (int j = 0; j < UNROLL; ++j) nxt[j] = xp[(size_t)j * n2];
            xp += (size_t)UNROLL * n2;
        }

        float2 z[UNROLL];
#pragma unroll
        for (int j = 0; j < UNROLL; ++j) {
            // v_dec = v + a * ((0 - v) + i)   [no FMA]
            float vd0 = __fadd_rn(v0, __fmul_rn(a, __fadd_rn(i0, -v0)));
            float vd1 = __fadd_rn(v1, __fmul_rn(a, __fadd_rn(i1, -v1)));
            // z = (v_dec - V_TH > 0)  <=>  v_dec > 1.0f in f32
            z[j].x = vd0 > 1.0f ? 1.0f : 0.0f;
            z[j].y = vd1 > 1.0f ? 1.0f : 0.0f;
            // v_new = (1-z)*v_dec + z*0  => select
            v0 = vd0 > 1.0f ? 0.0f : vd0;
            v1 = vd1 > 1.0f ? 0.0f : vd1;
            // i_new = i * b + x_t   [no FMA: mul then add]
            i0 = __fadd_rn(__fmul_rn(i0, b), cur[j].x);
            i1 = __fadd_rn(__fmul_rn(i1, b), cur[j].y);
        }

#pragma unroll
        for (int j = 0; j < UNROLL; ++j) op[(size_t)j * n2] = z[j];
        op += (size_t)UNROLL * n2;

#pragma unroll
        for (int j = 0; j < UNROLL; ++j) cur[j] = nxt[j];
    }
}

extern "C" void kernel_launch(void* const* d_in, const int* in_sizes, int n_in,
                              void* d_out, int out_size, void* d_ws, size_t ws_size,
                              hipStream_t stream) {
    const float* x   = (const float*)d_in[0];
    const float* tsi = (const float*)d_in[1];
    const float* tmi = (const float*)d_in[2];
    float* out = (float*)d_out;

    int total = in_sizes[0];          // T * B * H * W = 33554432
    int n  = total / T_STEPS;         // 131072 elements per timestep
    int n2 = n / 2;                   // float2 threads = 65536

    dim3 block(128);
    dim3 grid((n2 + block.x - 1) / block.x);   // 512 blocks
    hipLaunchKernelGGL(lif_kernel, grid, block, 0, stream,
                       (const float2*)x, (float2*)out, tsi, tmi, n2);
}

// Round 3
// 43.076 us; speedup vs baseline: 1.0311x; 1.0311x over previous
//
#include <hip/hip_runtime.h>

// LIF recurrence: x [T=256, B=32, H=64, W=64] f32 -> spikes same shape.
// Independent across the 131072 spatial elements; sequential over T.
//
// R1: 44.4us, logical 268MB => 6.05 TB/s (~96% of achievable HBM).
// rocprof showed FETCH_SIZE ~64 MiB = half the input: L3 (256 MiB) already
// retains ~50% of x across replays; the 128 MiB output write stream evicts
// the rest. R2/R3 change: NON-TEMPORAL stores for the output (never re-read)
// so the whole input stays L3-resident -> HBM floor becomes write-only
// (~134 MB ~ 21us) + L3-speed reads.
// R2 failed to compile: __builtin_nontemporal_store needs a native clang
// vector type, not HIP_vector_type<float,2>. R3 uses ext_vector_type(2).
//
// Numerics: reference (numpy/XLA f32) does NOT contract mul+add into FMA.
// Spikes are a hard threshold (v_dec > 1.0), so a single differently-rounded
// FMA can flip a spike (absmax jumps to 1.0). All recurrence arithmetic uses
// __fmul_rn/__fadd_rn/__fsub_rn to pin the exact f32 op sequence.

#define T_STEPS 256
#define UNROLL 8

typedef float f32x2 __attribute__((ext_vector_type(2)));

__global__ __launch_bounds__(128) void lif_kernel(
    const float2* __restrict__ x, float2* __restrict__ out,
    const float* __restrict__ tsi_p, const float* __restrict__ tmi_p,
    int n2)
{
    int idx = blockIdx.x * blockDim.x + threadIdx.x;
    if (idx >= n2) return;

    const float tmi = *tmi_p;
    const float tsi = *tsi_p;
    // a = DT * tau_mem_inv ; b = 1 - DT * tau_syn_inv  (exact ref op order)
    const float a = __fmul_rn(0.001f, tmi);
    const float b = __fsub_rn(1.0f, __fmul_rn(0.001f, tsi));

    const float2* xp = x + idx;
    f32x2*        op = (f32x2*)out + idx;

    float v0 = 0.f, i0 = 0.f, v1 = 0.f, i1 = 0.f;
    float2 cur[UNROLL], nxt[UNROLL];

#pragma unroll
    for (int j = 0; j < UNROLL; ++j) cur[j] = xp[(size_t)j * n2];
    xp += (size_t)UNROLL * n2;

    for (int t = 0; t < T_STEPS; t += UNROLL) {
        // prefetch next chunk while computing current (double buffer)
        if (t + UNROLL < T_STEPS) {
#pragma unroll
            for (int j = 0; j < UNROLL; ++j) nxt[j] = xp[(size_t)j * n2];
            xp += (size_t)UNROLL * n2;
        }

        f32x2 z[UNROLL];
#pragma unroll
        for (int j = 0; j < UNROLL; ++j) {
            // v_dec = v + a * ((0 - v) + i)   [no FMA]
            float vd0 = __fadd_rn(v0, __fmul_rn(a, __fadd_rn(i0, -v0)));
            float vd1 = __fadd_rn(v1, __fmul_rn(a, __fadd_rn(i1, -v1)));
            // z = (v_dec - V_TH > 0)  <=>  v_dec > 1.0f in f32
            z[j].x = vd0 > 1.0f ? 1.0f : 0.0f;
            z[j].y = vd1 > 1.0f ? 1.0f : 0.0f;
            // v_new = (1-z)*v_dec + z*0  => select
            v0 = vd0 > 1.0f ? 0.0f : vd0;
            v1 = vd1 > 1.0f ? 0.0f : vd1;
            // i_new = i * b + x_t   [no FMA: mul then add]
            i0 = __fadd_rn(__fmul_rn(i0, b), cur[j].x);
            i1 = __fadd_rn(__fmul_rn(i1, b), cur[j].y);
        }

        // Non-temporal stores: output is write-once/never-read; keep it out
        // of L2/L3 so the input x stays LLC-resident across graph replays.
#pragma unroll
        for (int j = 0; j < UNROLL; ++j)
            __builtin_nontemporal_store(z[j], &op[(size_t)j * n2]);
        op += (size_t)UNROLL * n2;

#pragma unroll
        for (int j = 0; j < UNROLL; ++j) cur[j] = nxt[j];
    }
}

extern "C" void kernel_launch(void* const* d_in, const int* in_sizes, int n_in,
                              void* d_out, int out_size, void* d_ws, size_t ws_size,
                              hipStream_t stream) {
    const float* x   = (const float*)d_in[0];
    const float* tsi = (const float*)d_in[1];
    const float* tmi = (const float*)d_in[2];
    float* out = (float*)d_out;

    int total = in_sizes[0];          // T * B * H * W = 33554432
    int n  = total / T_STEPS;         // 131072 elements per timestep
    int n2 = n / 2;                   // float2 threads = 65536

    dim3 block(128);
    dim3 grid((n2 + block.x - 1) / block.x);   // 512 blocks
    hipLaunchKernelGGL(lif_kernel, grid, block, 0, stream,
                       (const float2*)x, (float2*)out, tsi, tmi, n2);
}